// Round 1
// baseline (351.216 us; speedup 1.0000x reference)
//
#include <hip/hip_runtime.h>
#include <math.h>

#define MAXC 16  // max_num_children per the reference (also read on device for indexing math)

// Kernel 1: recover per-group start offsets from flat_index.
// flat_index[j] = group*MC + col, strictly increasing, every group has col==0.
// offs[g] = first score index of group g; offs[num_internal] = n_scores.
__global__ void build_offsets_kernel(const int* __restrict__ flat_index,
                                     const int* __restrict__ p_num_internal,
                                     const int* __restrict__ p_max_children,
                                     int n_scores,
                                     int* __restrict__ offs) {
    int j = blockIdx.x * blockDim.x + threadIdx.x;
    int mc = p_max_children[0];
    if (j < n_scores) {
        int fi = flat_index[j];
        if (fi % mc == 0) offs[fi / mc] = j;
    }
    if (j == 0) offs[p_num_internal[0]] = n_scores;
}

// Kernel 2: grouped log-softmax, one thread per (batch row, group).
// out[b,0] = 0 ; out[b, 1+j] = scores[b,j] - logsumexp(group(j)).
__global__ void __launch_bounds__(256)
hier_logsoftmax_kernel(const float* __restrict__ scores,
                       const int* __restrict__ offs,
                       const int* __restrict__ p_num_internal,
                       float* __restrict__ out,
                       int n_scores, int num_nodes) {
    const int ni = p_num_internal[0];
    const int b = blockIdx.y;
    const float* __restrict__ srow = scores + (size_t)b * (size_t)n_scores;
    float* __restrict__ orow = out + (size_t)b * (size_t)num_nodes;

    if (blockIdx.x == 0 && threadIdx.x == 0) orow[0] = 0.0f;  // root stays 0

    for (int i = blockIdx.x * blockDim.x + threadIdx.x; i < ni;
         i += gridDim.x * blockDim.x) {
        const int o0 = offs[i];
        const int c  = offs[i + 1] - o0;  // 2..16

        // Fully-unrolled predicated loads -> registers (no scratch).
        float v[MAXC];
        #pragma unroll
        for (int k = 0; k < MAXC; ++k)
            v[k] = (k < c) ? srow[o0 + k] : -INFINITY;

        float m = v[0];
        #pragma unroll
        for (int k = 1; k < MAXC; ++k) m = fmaxf(m, v[k]);

        float s = 0.0f;
        #pragma unroll
        for (int k = 0; k < MAXC; ++k) s += __expf(v[k] - m);  // exp(-inf)=0 for pads

        const float lse = m + __logf(s);

        #pragma unroll
        for (int k = 0; k < MAXC; ++k)
            if (k < c) orow[1 + o0 + k] = v[k] - lse;
    }
}

extern "C" void kernel_launch(void* const* d_in, const int* in_sizes, int n_in,
                              void* d_out, int out_size, void* d_ws, size_t ws_size,
                              hipStream_t stream) {
    const float* scores     = (const float*)d_in[0];
    const int*   flat_index = (const int*)d_in[1];
    // d_in[2] = child_index (== arange(1,num_nodes), not needed)
    const int*   p_ni       = (const int*)d_in[3];  // num_internal (device scalar)
    const int*   p_mc       = (const int*)d_in[4];  // max_num_children (device scalar)

    const int n_scores  = in_sizes[1];
    const int batch     = in_sizes[0] / n_scores;
    const int num_nodes = out_size / batch;

    int*   offs = (int*)d_ws;           // (num_internal+1) ints, rebuilt every call
    float* out  = (float*)d_out;

    // Kernel 1: build group offsets.
    {
        dim3 blk(256), grd((n_scores + 255) / 256);
        hipLaunchKernelGGL(build_offsets_kernel, grd, blk, 0, stream,
                           flat_index, p_ni, p_mc, n_scores, offs);
    }

    // Kernel 2: main compute. grid.x * 256 = 4096 thread slots per batch row,
    // stride loop covers the device-read group count (4000 for this problem).
    {
        dim3 blk(256), grd(16, batch);
        hipLaunchKernelGGL(hier_logsoftmax_kernel, grd, blk, 0, stream,
                           scores, offs, p_ni, out, n_scores, num_nodes);
    }
}

// Round 2
// 276.139 us; speedup vs baseline: 1.2719x; 1.2719x over previous
//
#include <hip/hip_runtime.h>
#include <math.h>

#define MAXC 16              // max_num_children (matches reference MAX_CHILDREN)
#define GPB  256             // groups per block
#define BLOCK 256
#define LBUF_SZ (GPB * MAXC + 32)   // span (<=4096) + alignment pad (<=3) + over-read pad (<=15)

// Kernel 1: recover per-group start offsets from flat_index.
// flat_index[j] = group*mc + col, strictly increasing, every group has col==0.
// offs[g] = first score index of group g; offs[num_internal] = n_scores.
__global__ void build_offsets_kernel(const int* __restrict__ flat_index,
                                     const int* __restrict__ p_num_internal,
                                     const int* __restrict__ p_max_children,
                                     int n_scores,
                                     int* __restrict__ offs) {
    int j = blockIdx.x * blockDim.x + threadIdx.x;
    int mc = p_max_children[0];
    if (j < n_scores) {
        int fi = flat_index[j];
        if (fi % mc == 0) offs[fi / mc] = j;
    }
    if (j == 0) offs[p_num_internal[0]] = n_scores;
}

// Kernel 2: grouped log-softmax via LDS staging.
// out[b,0] = 0 ; out[b, 1+j] = scores[b,j] - logsumexp(group(j)).
__global__ void __launch_bounds__(BLOCK)
hier_logsoftmax_kernel(const float* __restrict__ scores,
                       const int* __restrict__ offs,
                       const int* __restrict__ p_num_internal,
                       float* __restrict__ out,
                       int n_scores, int num_nodes) {
    __shared__ __align__(16) float lbuf[LBUF_SZ];

    const int ni = p_num_internal[0];
    const int nchunks = (ni + GPB - 1) / GPB;
    const int b = blockIdx.y;
    const float* __restrict__ srow = scores + (size_t)b * (size_t)n_scores;
    float* __restrict__ orow = out + (size_t)b * (size_t)num_nodes;

    for (int chunk = blockIdx.x; chunk < nchunks; chunk += gridDim.x) {
        const int g0   = chunk * GPB;
        const int gend = min(g0 + GPB, ni);
        const int e0   = offs[g0];
        const int e1   = offs[gend];
        const int n    = e1 - e0;          // <= GPB*MAXC
        const int d    = e0 & 3;           // lbuf[d+i] holds element e0+i (load-side 16B alignment)

        // ---- load phase: coalesced global -> LDS, float4 body ----
        {
            const int hL  = min(n, (4 - (e0 & 3)) & 3);      // scalars until 16B-aligned
            const int nvL = (n - hL) >> 2;                   // float4 count
            for (int q = threadIdx.x; q < nvL; q += BLOCK) {
                const int i = hL + 4 * q;
                const float4 t = *(const float4*)&srow[e0 + i];   // aligned
                *(float4*)&lbuf[d + i] = t;                        // aligned (d+hL ≡ 0 mod 4)
            }
            for (int i = hL + 4 * nvL + threadIdx.x; i < n; i += BLOCK)
                lbuf[d + i] = srow[e0 + i];
            if (threadIdx.x < hL) lbuf[d + threadIdx.x] = srow[e0 + threadIdx.x];
        }
        __syncthreads();

        // ---- compute phase: one thread per group ----
        {
            const int g = g0 + threadIdx.x;
            if (g < gend) {
                const int lo = d + (offs[g] - e0);
                const int c  = offs[g + 1] - offs[g];        // 2..MAXC
                float v[MAXC];
                #pragma unroll
                for (int k = 0; k < MAXC; ++k) v[k] = lbuf[lo + k];  // over-read OK (padded)
                float m = -INFINITY;
                #pragma unroll
                for (int k = 0; k < MAXC; ++k) m = fmaxf(m, (k < c) ? v[k] : -INFINITY);
                float s = 0.0f;
                #pragma unroll
                for (int k = 0; k < MAXC; ++k) s += (k < c) ? __expf(v[k] - m) : 0.0f;
                const float lse = m + __logf(s);
                #pragma unroll
                for (int k = 0; k < MAXC; ++k)
                    if (k < c) lbuf[lo + k] = v[k] - lse;
            }
        }
        __syncthreads();

        // ---- store phase: LDS -> coalesced global (+1 shift for root), float4 body ----
        {
            const int hS  = min(n, (4 - ((1 + e0) & 3)) & 3);
            const int nvS = (n - hS) >> 2;
            for (int q = threadIdx.x; q < nvS; q += BLOCK) {
                const int i = hS + 4 * q;
                float4 t;
                t.x = lbuf[d + i];     t.y = lbuf[d + i + 1];
                t.z = lbuf[d + i + 2]; t.w = lbuf[d + i + 3];
                *(float4*)&orow[1 + e0 + i] = t;                   // aligned
            }
            for (int i = hS + 4 * nvS + threadIdx.x; i < n; i += BLOCK)
                orow[1 + e0 + i] = lbuf[d + i];
            if (threadIdx.x < hS) orow[1 + e0 + threadIdx.x] = lbuf[d + threadIdx.x];
        }
        if (chunk == 0 && threadIdx.x == 0) orow[0] = 0.0f;   // root stays 0
        __syncthreads();   // safe reuse of lbuf if this block loops
    }
}

extern "C" void kernel_launch(void* const* d_in, const int* in_sizes, int n_in,
                              void* d_out, int out_size, void* d_ws, size_t ws_size,
                              hipStream_t stream) {
    const float* scores     = (const float*)d_in[0];
    const int*   flat_index = (const int*)d_in[1];
    // d_in[2] = child_index (== arange(1,num_nodes), not needed)
    const int*   p_ni       = (const int*)d_in[3];  // num_internal (device scalar)
    const int*   p_mc       = (const int*)d_in[4];  // max_num_children (device scalar)

    const int n_scores  = in_sizes[1];
    const int batch     = in_sizes[0] / n_scores;
    const int num_nodes = out_size / batch;

    int*   offs = (int*)d_ws;           // (num_internal+1) ints, rebuilt every call
    float* out  = (float*)d_out;

    // Kernel 1: build group offsets.
    {
        dim3 blk(256), grd((n_scores + 255) / 256);
        hipLaunchKernelGGL(build_offsets_kernel, grd, blk, 0, stream,
                           flat_index, p_ni, p_mc, n_scores, offs);
    }

    // Kernel 2: main compute. 16 chunk-blocks x batch rows; block-stride loop
    // covers any device-side group count.
    {
        dim3 blk(BLOCK), grd(16, batch);
        hipLaunchKernelGGL(hier_logsoftmax_kernel, grd, blk, 0, stream,
                           scores, offs, p_ni, out, n_scores, num_nodes);
    }
}

// Round 3
// 271.486 us; speedup vs baseline: 1.2937x; 1.0171x over previous
//
#include <hip/hip_runtime.h>
#include <math.h>

#define MAXC 16              // max_num_children (matches reference MAX_CHILDREN)
#define GPB  256             // groups per block
#define BLOCK 256
#define LBUF_SZ (GPB * MAXC + 32)   // span (<=4096) + alignment pad (<=3) + over-read pad (<=15)

// Kernel 1: per-group start offsets + per-element group id (uint16).
// flat_index[j] = g*mc + col, strictly increasing, every group has col==0.
__global__ void build_meta_kernel(const int* __restrict__ flat_index,
                                  const int* __restrict__ p_num_internal,
                                  const int* __restrict__ p_max_children,
                                  int n_scores,
                                  int* __restrict__ offs,
                                  unsigned short* __restrict__ gid16) {
    int j = blockIdx.x * blockDim.x + threadIdx.x;
    int mc = p_max_children[0];
    if (j < n_scores) {
        int fi = flat_index[j];
        int g  = fi / mc;
        gid16[j] = (unsigned short)g;
        if (fi - g * mc == 0) offs[g] = j;
    }
    if (j == 0) offs[p_num_internal[0]] = n_scores;
}

// Kernel 2: grouped log-softmax via LDS staging + lse side-array.
// out[b,0] = 0 ; out[b, 1+j] = scores[b,j] - logsumexp(group(j)).
__global__ void __launch_bounds__(BLOCK)
hier_logsoftmax_kernel(const float* __restrict__ scores,
                       const int* __restrict__ offs,
                       const unsigned short* __restrict__ gid16,
                       const int* __restrict__ p_num_internal,
                       float* __restrict__ out,
                       int n_scores, int num_nodes) {
    __shared__ __align__(16) float lbuf[LBUF_SZ];
    __shared__ float lse[GPB];

    const int ni = p_num_internal[0];
    const int nchunks = (ni + GPB - 1) / GPB;
    const int b = blockIdx.y;
    const float* __restrict__ srow = scores + (size_t)b * (size_t)n_scores;
    float* __restrict__ orow = out + (size_t)b * (size_t)num_nodes;

    for (int chunk = blockIdx.x; chunk < nchunks; chunk += gridDim.x) {
        const int g0   = chunk * GPB;
        const int gend = min(g0 + GPB, ni);
        const int e0   = offs[g0];
        const int e1   = offs[gend];
        const int n    = e1 - e0;          // <= GPB*MAXC
        const int d    = e0 & 3;           // lbuf[d+i] holds element e0+i (load-side 16B alignment)

        // ---- load phase: coalesced global -> LDS, float4 body ----
        {
            const int hL  = min(n, (4 - (e0 & 3)) & 3);      // scalars until 16B-aligned
            const int nvL = (n - hL) >> 2;                   // float4 count
            for (int q = threadIdx.x; q < nvL; q += BLOCK) {
                const int i = hL + 4 * q;
                const float4 t = *(const float4*)&srow[e0 + i];   // aligned
                *(float4*)&lbuf[d + i] = t;                        // aligned (d+hL ≡ 0 mod 4)
            }
            for (int i = hL + 4 * nvL + threadIdx.x; i < n; i += BLOCK)
                lbuf[d + i] = srow[e0 + i];
            if (threadIdx.x < hL) lbuf[d + threadIdx.x] = srow[e0 + threadIdx.x];
        }
        __syncthreads();

        // ---- compute phase: one thread per group, write lse only ----
        {
            const int g = g0 + threadIdx.x;
            if (g < gend) {
                const int og = offs[g];
                const int lo = d + (og - e0);
                const int c  = offs[g + 1] - og;             // 2..MAXC
                float v[MAXC];
                #pragma unroll
                for (int k = 0; k < MAXC; ++k)
                    v[k] = (k < c) ? lbuf[lo + k] : -INFINITY;  // single mask here only
                float m = v[0];
                #pragma unroll
                for (int k = 1; k < MAXC; ++k) m = fmaxf(m, v[k]);
                float s = 0.0f;
                #pragma unroll
                for (int k = 0; k < MAXC; ++k) s += __expf(v[k] - m);  // exp(-inf)=0 pads
                lse[threadIdx.x] = m + __logf(s);
            }
        }
        __syncthreads();

        // ---- store phase: out = staged - lse[gid], coalesced float4 ----
        {
            const unsigned short* __restrict__ grow = gid16 + e0;
            const int hS  = min(n, (4 - ((1 + e0) & 3)) & 3);
            const int nvS = (n - hS) >> 2;
            for (int q = threadIdx.x; q < nvS; q += BLOCK) {
                const int i = hS + 4 * q;
                float4 t;
                t.x = lbuf[d + i]     - lse[grow[i]     - g0];
                t.y = lbuf[d + i + 1] - lse[grow[i + 1] - g0];
                t.z = lbuf[d + i + 2] - lse[grow[i + 2] - g0];
                t.w = lbuf[d + i + 3] - lse[grow[i + 3] - g0];
                *(float4*)&orow[1 + e0 + i] = t;                   // aligned
            }
            for (int i = hS + 4 * nvS + threadIdx.x; i < n; i += BLOCK)
                orow[1 + e0 + i] = lbuf[d + i] - lse[grow[i] - g0];
            if (threadIdx.x < hS)
                orow[1 + e0 + threadIdx.x] = lbuf[d + threadIdx.x] - lse[grow[threadIdx.x] - g0];
        }
        if (chunk == 0 && threadIdx.x == 0) orow[0] = 0.0f;   // root stays 0
        __syncthreads();   // safe reuse of lbuf/lse if this block loops
    }
}

extern "C" void kernel_launch(void* const* d_in, const int* in_sizes, int n_in,
                              void* d_out, int out_size, void* d_ws, size_t ws_size,
                              hipStream_t stream) {
    const float* scores     = (const float*)d_in[0];
    const int*   flat_index = (const int*)d_in[1];
    // d_in[2] = child_index (== arange(1,num_nodes), not needed)
    const int*   p_ni       = (const int*)d_in[3];  // num_internal (device scalar)
    const int*   p_mc       = (const int*)d_in[4];  // max_num_children (device scalar)

    const int n_scores  = in_sizes[1];
    const int batch     = in_sizes[0] / n_scores;
    const int num_nodes = out_size / batch;

    // Workspace layout: offs (num_internal+1 ints), then gid16 (n_scores u16).
    int* offs = (int*)d_ws;
    unsigned short* gid16 = (unsigned short*)((char*)d_ws + ((size_t)(n_scores + 2) * 4 + 255 & ~(size_t)255));
    float* out = (float*)d_out;

    // Kernel 1: build group offsets + per-element gid.
    {
        dim3 blk(256), grd((n_scores + 255) / 256);
        hipLaunchKernelGGL(build_meta_kernel, grd, blk, 0, stream,
                           flat_index, p_ni, p_mc, n_scores, offs, gid16);
    }

    // Kernel 2: main compute. 16 chunk-blocks x batch rows; block-stride loop
    // covers any device-side group count.
    {
        dim3 blk(BLOCK), grd(16, batch);
        hipLaunchKernelGGL(hier_logsoftmax_kernel, grd, blk, 0, stream,
                           scores, offs, gid16, p_ni, out, n_scores, num_nodes);
    }
}